// Round 3
// baseline (681.086 us; speedup 1.0000x reference)
//
#include <hip/hip_runtime.h>

#define E_DIM 512
#define U_DIM 64
#define T_DIM 8
#define A_DIM 32
#define NB    10
#define BATCH 8192
#define G     4                      // same-type elements per block
#define MAX_BLOCKS (BATCH / G + T_DIM)

// workspace layout (ints)
#define WS_PERM  0                   // [8192] permutation, grouped by type
#define WS_START 8192                // [9] element-range prefix per type
#define WS_BLK   8201                // [9] block-range prefix per type
#define WS_INTS  8210

// ---------------------------------------------------------------------------
// Pass 1: counting sort of batch elements by type (order within type is
// irrelevant -- every element's arithmetic is independent -- so atomic
// nondeterminism does not affect the output).
// ---------------------------------------------------------------------------
__global__ void bucket_kernel(const int* __restrict__ train_types,
                              int* __restrict__ ws)
{
    __shared__ int cnt[T_DIM], offs[T_DIM], startS[T_DIM];
    const int tid  = threadIdx.x;        // 1024 threads, 16 waves
    const int lane = tid & 63;

    if (tid < T_DIM) { cnt[tid] = 0; offs[tid] = 0; }
    __syncthreads();

    int ty[8];
    #pragma unroll
    for (int it = 0; it < 8; ++it) ty[it] = train_types[tid + it * 1024];

    // wave-aggregated counting: <=8 LDS atomics per wave per iter
    #pragma unroll
    for (int it = 0; it < 8; ++it) {
        #pragma unroll
        for (int t = 0; t < T_DIM; ++t) {
            const unsigned long long m = __ballot(ty[it] == t);
            if (m && lane == __ffsll((unsigned long long)m) - 1)
                atomicAdd(&cnt[t], __popcll(m));
        }
    }
    __syncthreads();

    if (tid == 0) {
        int s = 0, bs = 0;
        for (int t = 0; t < T_DIM; ++t) {
            startS[t] = s;
            ws[WS_START + t] = s;
            ws[WS_BLK + t]   = bs;
            s  += cnt[t];
            bs += (cnt[t] + G - 1) / G;
        }
        ws[WS_START + T_DIM] = s;    // = BATCH
        ws[WS_BLK + T_DIM]   = bs;   // total live blocks
    }
    __syncthreads();

    // scatter with wave-aggregated rank
    #pragma unroll
    for (int it = 0; it < 8; ++it) {
        const int idx = tid + it * 1024;
        const int t   = ty[it];
        #pragma unroll
        for (int tt = 0; tt < T_DIM; ++tt) {
            const unsigned long long m = __ballot(t == tt);
            if (t == tt) {
                const int leader = __ffsll((unsigned long long)m) - 1;
                int base;
                if (lane == leader) base = atomicAdd(&offs[tt], __popcll(m));
                base = __shfl(base, leader, 64);
                const int rank = __popcll(m & ((1ull << lane) - 1ull));
                ws[WS_PERM + startS[tt] + base + rank] = idx;
            }
        }
    }
}

// ---------------------------------------------------------------------------
// Pass 2: G=4 same-type elements per block, 4 waves. Wave g owns element g
// (gather + attention + in-register softmax/agg); the final rank-64 matvec is
// cooperative: one w[ty] load stream feeds all 4 elements (4x less L2 traffic,
// 8 FMA per w-load instead of 2).
// ---------------------------------------------------------------------------
__launch_bounds__(256, 8)
__global__ void gatne_main(
    const float* __restrict__ node_embeddings,      // [N, 512]
    const float* __restrict__ node_type_embeddings, // [N, 8, 64]
    const float* __restrict__ trans_weights,        // [8, 64, 512]
    const float* __restrict__ trans_weights_s1,     // [8, 64, 32]
    const float* __restrict__ trans_weights_s2,     // [8, 32]
    const int*   __restrict__ train_inputs,         // [B]
    const int*   __restrict__ node_neigh,           // [B, 8, 10]
    const int*   __restrict__ ws,
    float*       __restrict__ out)                  // [B, 512]
{
    const int tid  = threadIdx.x;
    const int lane = tid & 63;
    const int wv   = tid >> 6;

    __shared__ float s_nte[G][T_DIM][U_DIM];            // 8 KB
    __shared__ __align__(16) float s_agg[U_DIM][G];     // 1 KB, [u][g] for b128 read
    __shared__ float s_red[4][G];

    const int j = blockIdx.x;
    if (j >= ws[WS_BLK + T_DIM]) return;

    // block -> (type, element range): linear scan of 8-entry prefix (uniform)
    int t = 0;
    #pragma unroll
    for (int k = 1; k < T_DIM; ++k) if (j >= ws[WS_BLK + k]) t = k;
    const int eStart = ws[WS_START + t];
    const int eEnd   = ws[WS_START + t + 1];
    const int eBase  = eStart + (j - ws[WS_BLK + t]) * G;
    const int nE     = min(G, eEnd - eBase);

    int eIdx[G];
    #pragma unroll
    for (int g = 0; g < G; ++g)
        eIdx[g] = ws[WS_PERM + eBase + min(g, nE - 1)];   // clamp tail (stores masked)

    // prefetch node_embed rows early (hide under gather)
    const int e0 = tid * 2;
    float2 ne[G];
    #pragma unroll
    for (int g = 0; g < G; ++g)
        ne[g] = *(const float2*)(node_embeddings + (size_t)train_inputs[eIdx[g]] * E_DIM + e0);

    // wave's own element index (avoid runtime-indexing the register array)
    const int myE = (wv == 0) ? eIdx[0] : (wv == 1) ? eIdx[1] : (wv == 2) ? eIdx[2] : eIdx[3];

    // ---- gather + neighbor-sum for element `wv`: acc[tt] over all 8 types ----
    const int* nn = node_neigh + (size_t)myE * (T_DIM * NB);
    const int i0 = nn[lane];
    const int i1 = (lane < (T_DIM * NB - 64)) ? nn[64 + lane] : 0;
    float acc[T_DIM];
    #pragma unroll
    for (int tt = 0; tt < T_DIM; ++tt) {
        float a = 0.f;
        #pragma unroll
        for (int n = 0; n < NB; ++n) {
            const int jj  = tt * NB + n;
            const int nbi = (jj < 64) ? __shfl(i0, jj, 64) : __shfl(i1, jj - 64, 64);
            a += node_type_embeddings[(size_t)nbi * (T_DIM * U_DIM) + tt * U_DIM + lane];
        }
        acc[tt] = a;
        s_nte[wv][tt][lane] = a;
    }
    __builtin_amdgcn_wave_barrier();   // intra-wave LDS write->read ordering

    // ---- attention for element `wv`: lane (half=lane>>5, a=lane&31) ----
    const int a_idx = lane & 31;
    const int half  = lane >> 5;
    const float* w1 = trans_weights_s1 + (size_t)t * (U_DIM * A_DIM) + a_idx;
    float h0 = 0.f, h1 = 0.f, h2 = 0.f, h3 = 0.f;
    #pragma unroll
    for (int u = 0; u < U_DIM; ++u) {
        const float wv1 = w1[u * A_DIM];               // L1-hot: shared by same-type blocks
        h0 = fmaf(s_nte[wv][half + 0][u], wv1, h0);
        h1 = fmaf(s_nte[wv][half + 2][u], wv1, h1);
        h2 = fmaf(s_nte[wv][half + 4][u], wv1, h2);
        h3 = fmaf(s_nte[wv][half + 6][u], wv1, h3);
    }
    const float w2v = trans_weights_s2[t * A_DIM + a_idx];
    h0 = tanhf(h0) * w2v;  h1 = tanhf(h1) * w2v;
    h2 = tanhf(h2) * w2v;  h3 = tanhf(h3) * w2v;
    #pragma unroll
    for (int off = 16; off > 0; off >>= 1) {
        h0 += __shfl_down(h0, off, 32);
        h1 += __shfl_down(h1, off, 32);
        h2 += __shfl_down(h2, off, 32);
        h3 += __shfl_down(h3, off, 32);
    }
    const float sc0 = __shfl(h0, 0, 64),  sc2 = __shfl(h1, 0, 64);
    const float sc4 = __shfl(h2, 0, 64),  sc6 = __shfl(h3, 0, 64);
    const float sc1 = __shfl(h0, 32, 64), sc3 = __shfl(h1, 32, 64);
    const float sc5 = __shfl(h2, 32, 64), sc7 = __shfl(h3, 32, 64);

    // softmax over 8 types, redundant per lane (pure VALU)
    const float m = fmaxf(fmaxf(fmaxf(sc0, sc1), fmaxf(sc2, sc3)),
                          fmaxf(fmaxf(sc4, sc5), fmaxf(sc6, sc7)));
    const float x0 = __expf(sc0 - m), x1 = __expf(sc1 - m);
    const float x2 = __expf(sc2 - m), x3 = __expf(sc3 - m);
    const float x4 = __expf(sc4 - m), x5 = __expf(sc5 - m);
    const float x6 = __expf(sc6 - m), x7 = __expf(sc7 - m);
    const float inv_sum = 1.f / (x0 + x1 + x2 + x3 + x4 + x5 + x6 + x7);

    // agg[u=lane] straight from register accumulators
    const float agg = (x0 * acc[0] + x1 * acc[1] + x2 * acc[2] + x3 * acc[3] +
                       x4 * acc[4] + x5 * acc[5] + x6 * acc[6] + x7 * acc[7]) * inv_sum;
    s_agg[lane][wv] = agg;
    __syncthreads();

    // ---- cooperative rank-64 matvec: out[g][e] = ne[g][e] + sum_u agg[g][u]*w[t][u][e]
    const float* wb = trans_weights + (size_t)t * (U_DIM * E_DIM) + e0;
    float2 v0 = ne[0], v1 = ne[1], v2 = ne[2], v3 = ne[3];
    #pragma unroll 16
    for (int u = 0; u < U_DIM; ++u) {
        const float2 wv2 = *(const float2*)(wb + (size_t)u * E_DIM);
        const float4 ag  = *(const float4*)(&s_agg[u][0]);   // ds_read_b128 broadcast
        v0.x = fmaf(ag.x, wv2.x, v0.x);  v0.y = fmaf(ag.x, wv2.y, v0.y);
        v1.x = fmaf(ag.y, wv2.x, v1.x);  v1.y = fmaf(ag.y, wv2.y, v1.y);
        v2.x = fmaf(ag.z, wv2.x, v2.x);  v2.y = fmaf(ag.z, wv2.y, v2.y);
        v3.x = fmaf(ag.w, wv2.x, v3.x);  v3.y = fmaf(ag.w, wv2.y, v3.y);
    }

    // ---- per-element L2 norm: wave butterfly + cross-wave LDS combine ----
    float ss0 = v0.x * v0.x + v0.y * v0.y;
    float ss1 = v1.x * v1.x + v1.y * v1.y;
    float ss2 = v2.x * v2.x + v2.y * v2.y;
    float ss3 = v3.x * v3.x + v3.y * v3.y;
    #pragma unroll
    for (int off = 32; off > 0; off >>= 1) {
        ss0 += __shfl_xor(ss0, off, 64);
        ss1 += __shfl_xor(ss1, off, 64);
        ss2 += __shfl_xor(ss2, off, 64);
        ss3 += __shfl_xor(ss3, off, 64);
    }
    if (lane == 0) {
        s_red[wv][0] = ss0; s_red[wv][1] = ss1;
        s_red[wv][2] = ss2; s_red[wv][3] = ss3;
    }
    __syncthreads();
    float tot[G];
    #pragma unroll
    for (int g = 0; g < G; ++g)
        tot[g] = s_red[0][g] + s_red[1][g] + s_red[2][g] + s_red[3][g];

    const float iv0 = 1.f / fmaxf(sqrtf(tot[0]), 1e-12f);
    const float iv1 = 1.f / fmaxf(sqrtf(tot[1]), 1e-12f);
    const float iv2 = 1.f / fmaxf(sqrtf(tot[2]), 1e-12f);
    const float iv3 = 1.f / fmaxf(sqrtf(tot[3]), 1e-12f);

    {
        float2 o; o.x = v0.x * iv0; o.y = v0.y * iv0;
        *(float2*)(out + (size_t)eIdx[0] * E_DIM + e0) = o;
    }
    if (1 < nE) { float2 o; o.x = v1.x * iv1; o.y = v1.y * iv1;
                  *(float2*)(out + (size_t)eIdx[1] * E_DIM + e0) = o; }
    if (2 < nE) { float2 o; o.x = v2.x * iv2; o.y = v2.y * iv2;
                  *(float2*)(out + (size_t)eIdx[2] * E_DIM + e0) = o; }
    if (3 < nE) { float2 o; o.x = v3.x * iv3; o.y = v3.y * iv3;
                  *(float2*)(out + (size_t)eIdx[3] * E_DIM + e0) = o; }
}

// ---------------------------------------------------------------------------
// Fallback (round-2 kernel) if workspace is too small for the bucketing path.
// ---------------------------------------------------------------------------
__launch_bounds__(256, 8)
__global__ void gatne_fallback(
    const float* __restrict__ node_embeddings,
    const float* __restrict__ node_type_embeddings,
    const float* __restrict__ trans_weights,
    const float* __restrict__ trans_weights_s1,
    const float* __restrict__ trans_weights_s2,
    const int*   __restrict__ train_inputs,
    const int*   __restrict__ train_types,
    const int*   __restrict__ node_neigh,
    float*       __restrict__ out)
{
    const int b    = blockIdx.x;
    const int tid  = threadIdx.x;
    const int lane = tid & 63;
    const int wv   = tid >> 6;

    __shared__ float s_nte[T_DIM][U_DIM];
    __shared__ float s_att[T_DIM];
    __shared__ float s_agg[U_DIM];
    __shared__ float s_red[4];

    const int* nn = node_neigh + (size_t)b * (T_DIM * NB);
    int my = 0;
    if (lane < 2 * NB) my = nn[wv * NB + (lane < NB ? lane : 30 + lane)];

    const int ni = train_inputs[b];
    const int ty = train_types[b];
    const int e0 = tid * 2;
    const float2 ne = *(const float2*)(node_embeddings + (size_t)ni * E_DIM + e0);

    float a0 = 0.f, a1 = 0.f;
    #pragma unroll
    for (int n = 0; n < NB; ++n) {
        const int i0 = __shfl(my, n, 64);
        const int i1 = __shfl(my, NB + n, 64);
        a0 += node_type_embeddings[(size_t)i0 * (T_DIM * U_DIM) + wv * U_DIM + lane];
        a1 += node_type_embeddings[(size_t)i1 * (T_DIM * U_DIM) + (wv + 4) * U_DIM + lane];
    }
    s_nte[wv][lane]     = a0;
    s_nte[wv + 4][lane] = a1;
    __syncthreads();

    {
        const int t = tid >> 5;
        const int a = tid & 31;
        const float* w1 = trans_weights_s1 + (size_t)ty * (U_DIM * A_DIM) + a;
        float h = 0.f;
        #pragma unroll
        for (int u = 0; u < U_DIM; ++u)
            h = fmaf(s_nte[t][u], w1[u * A_DIM], h);
        float val = tanhf(h) * trans_weights_s2[ty * A_DIM + a];
        #pragma unroll
        for (int off = 16; off > 0; off >>= 1)
            val += __shfl_down(val, off, 32);
        if (a == 0) s_att[t] = val;
    }
    __syncthreads();

    if (tid < U_DIM) {
        float sc0 = s_att[0], sc1 = s_att[1], sc2 = s_att[2], sc3 = s_att[3];
        float sc4 = s_att[4], sc5 = s_att[5], sc6 = s_att[6], sc7 = s_att[7];
        const float m = fmaxf(fmaxf(fmaxf(sc0, sc1), fmaxf(sc2, sc3)),
                              fmaxf(fmaxf(sc4, sc5), fmaxf(sc6, sc7)));
        const float x0 = __expf(sc0 - m), x1 = __expf(sc1 - m);
        const float x2 = __expf(sc2 - m), x3 = __expf(sc3 - m);
        const float x4 = __expf(sc4 - m), x5 = __expf(sc5 - m);
        const float x6 = __expf(sc6 - m), x7 = __expf(sc7 - m);
        const float inv_sum = 1.f / (x0 + x1 + x2 + x3 + x4 + x5 + x6 + x7);
        const float acc = x0 * s_nte[0][tid] + x1 * s_nte[1][tid]
                        + x2 * s_nte[2][tid] + x3 * s_nte[3][tid]
                        + x4 * s_nte[4][tid] + x5 * s_nte[5][tid]
                        + x6 * s_nte[6][tid] + x7 * s_nte[7][tid];
        s_agg[tid] = acc * inv_sum;
    }
    __syncthreads();

    const float* wb = trans_weights + (size_t)ty * (U_DIM * E_DIM) + e0;
    float v0 = ne.x, v1 = ne.y;
    #pragma unroll 16
    for (int u = 0; u < U_DIM; ++u) {
        const float av = s_agg[u];
        const float2 w2v = *(const float2*)(wb + (size_t)u * E_DIM);
        v0 = fmaf(av, w2v.x, v0);
        v1 = fmaf(av, w2v.y, v1);
    }

    float ss = v0 * v0 + v1 * v1;
    #pragma unroll
    for (int off = 32; off > 0; off >>= 1)
        ss += __shfl_xor(ss, off, 64);
    if (lane == 0) s_red[wv] = ss;
    __syncthreads();
    const float total = s_red[0] + s_red[1] + s_red[2] + s_red[3];
    const float inv = 1.f / fmaxf(sqrtf(total), 1e-12f);

    float2 o; o.x = v0 * inv; o.y = v1 * inv;
    *(float2*)(out + (size_t)b * E_DIM + e0) = o;
}

extern "C" void kernel_launch(void* const* d_in, const int* in_sizes, int n_in,
                              void* d_out, int out_size, void* d_ws, size_t ws_size,
                              hipStream_t stream) {
    const float* node_embeddings      = (const float*)d_in[0];
    const float* node_type_embeddings = (const float*)d_in[1];
    const float* trans_weights        = (const float*)d_in[2];
    const float* trans_weights_s1     = (const float*)d_in[3];
    const float* trans_weights_s2     = (const float*)d_in[4];
    const int*   train_inputs         = (const int*)d_in[5];
    const int*   train_types          = (const int*)d_in[6];
    const int*   node_neigh           = (const int*)d_in[7];
    float* out = (float*)d_out;

    if (d_ws != nullptr && ws_size >= WS_INTS * sizeof(int)) {
        bucket_kernel<<<1, 1024, 0, stream>>>(train_types, (int*)d_ws);
        gatne_main<<<MAX_BLOCKS, 256, 0, stream>>>(
            node_embeddings, node_type_embeddings, trans_weights,
            trans_weights_s1, trans_weights_s2,
            train_inputs, node_neigh, (const int*)d_ws, out);
    } else {
        gatne_fallback<<<BATCH, 256, 0, stream>>>(
            node_embeddings, node_type_embeddings, trans_weights,
            trans_weights_s1, trans_weights_s2,
            train_inputs, train_types, node_neigh, out);
    }
}

// Round 4
// 603.193 us; speedup vs baseline: 1.1291x; 1.1291x over previous
//
#include <hip/hip_runtime.h>

#define E_DIM 512
#define U_DIM 64
#define T_DIM 8
#define A_DIM 32
#define NB    10
#define BATCH 8192
#define G     4                      // same-type elements per block
#define MAX_BLOCKS (BATCH / G + T_DIM)

// workspace layout (ints)
#define WS_PERM  0                   // [8192] permutation, grouped by type
#define WS_START 8192                // [9] element-range prefix per type
#define WS_BLK   8201                // [9] block-range prefix per type
#define WS_INTS  8210

// ---------------------------------------------------------------------------
// Pass 1: counting sort of batch elements by type. Order within a type is
// irrelevant (each element's output depends only on its own inputs), so
// atomic nondeterminism in the permutation does not change the results.
// ---------------------------------------------------------------------------
__global__ void bucket_kernel(const int* __restrict__ train_types,
                              int* __restrict__ ws)
{
    __shared__ int cnt[T_DIM], offs[T_DIM], startS[T_DIM];
    const int tid  = threadIdx.x;        // 1024 threads, 16 waves
    const int lane = tid & 63;

    if (tid < T_DIM) { cnt[tid] = 0; offs[tid] = 0; }
    __syncthreads();

    int ty[8];
    #pragma unroll
    for (int it = 0; it < 8; ++it) ty[it] = train_types[tid + it * 1024];

    #pragma unroll
    for (int it = 0; it < 8; ++it) {
        #pragma unroll
        for (int t = 0; t < T_DIM; ++t) {
            const unsigned long long m = __ballot(ty[it] == t);
            if (m && lane == __ffsll((unsigned long long)m) - 1)
                atomicAdd(&cnt[t], __popcll(m));
        }
    }
    __syncthreads();

    if (tid == 0) {
        int s = 0, bs = 0;
        for (int t = 0; t < T_DIM; ++t) {
            startS[t] = s;
            ws[WS_START + t] = s;
            ws[WS_BLK + t]   = bs;
            s  += cnt[t];
            bs += (cnt[t] + G - 1) / G;
        }
        ws[WS_START + T_DIM] = s;
        ws[WS_BLK + T_DIM]   = bs;
    }
    __syncthreads();

    #pragma unroll
    for (int it = 0; it < 8; ++it) {
        const int idx = tid + it * 1024;
        const int t   = ty[it];
        #pragma unroll
        for (int tt = 0; tt < T_DIM; ++tt) {
            const unsigned long long m = __ballot(t == tt);
            if (t == tt) {
                const int leader = __ffsll((unsigned long long)m) - 1;
                int base;
                if (lane == leader) base = atomicAdd(&offs[tt], __popcll(m));
                base = __shfl(base, leader, 64);
                const int rank = __popcll(m & ((1ull << lane) - 1ull));
                ws[WS_PERM + startS[tt] + base + rank] = idx;
            }
        }
    }
}

// ---------------------------------------------------------------------------
// Pass 2: G=4 same-type elements per block, 4 waves. Wave g owns element g
// through gather+attention+softmax/agg; the rank-64 matvec is cooperative
// (one w[ty] float4 load stream feeds all 4 elements).
// Register discipline (round-3 spilled via an 80-deep unrolled gather):
//  - gather unrolled only 2x (20 loads in flight, like the 121us round-2 kernel)
//  - no register acc[] array: sums live in s_nte, re-read in the agg phase
//  - eIdx / ne rows are loaded only in the phase that needs them
// ---------------------------------------------------------------------------
__launch_bounds__(256, 8)
__global__ void gatne_main(
    const float* __restrict__ node_embeddings,      // [N, 512]
    const float* __restrict__ node_type_embeddings, // [N, 8, 64]
    const float* __restrict__ trans_weights,        // [8, 64, 512]
    const float* __restrict__ trans_weights_s1,     // [8, 64, 32]
    const float* __restrict__ trans_weights_s2,     // [8, 32]
    const int*   __restrict__ train_inputs,         // [B]
    const int*   __restrict__ node_neigh,           // [B, 8, 10]
    const int*   __restrict__ ws,
    float*       __restrict__ out)                  // [B, 512]
{
    const int tid  = threadIdx.x;
    const int lane = tid & 63;
    const int wv   = tid >> 6;

    __shared__ float s_nte[G][T_DIM][U_DIM];            // 8 KB
    __shared__ __align__(16) float s_agg[U_DIM][G];     // 1 KB, [u][g] -> b128 bcast
    __shared__ float s_red[2][G];

    const int j = blockIdx.x;
    if (j >= ws[WS_BLK + T_DIM]) return;

    // block -> (type, element range): 8-entry prefix scan (block-uniform)
    int t = 0;
    #pragma unroll
    for (int k = 1; k < T_DIM; ++k) if (j >= ws[WS_BLK + k]) t = k;
    const int eStart = ws[WS_START + t];
    const int eEnd   = ws[WS_START + t + 1];
    const int eBase  = eStart + (j - ws[WS_BLK + t]) * G;
    const int nE     = min(G, eEnd - eBase);

    // wave's own element (wave-uniform scalar load); tail waves duplicate last
    const int myE = ws[WS_PERM + eBase + min(wv, nE - 1)];

    // ---- gather + neighbor-sum for element `wv` over all 8 types ----
    const int* nn = node_neigh + (size_t)myE * (T_DIM * NB);
    const int i0 = nn[lane];
    const int i1 = (lane < (T_DIM * NB - 64)) ? nn[64 + lane] : 0;
    #pragma unroll 2
    for (int tt = 0; tt < T_DIM; ++tt) {
        float a = 0.f;
        #pragma unroll
        for (int n = 0; n < NB; ++n) {
            const int jj  = tt * NB + n;
            const int nbi = (jj < 64) ? __shfl(i0, jj, 64) : __shfl(i1, jj - 64, 64);
            a += node_type_embeddings[(size_t)nbi * (T_DIM * U_DIM) + tt * U_DIM + lane];
        }
        s_nte[wv][tt][lane] = a;
    }
    __builtin_amdgcn_wave_barrier();   // intra-wave LDS write->read ordering

    // ---- attention for element `wv`: lane (half=lane>>5, a=lane&31) ----
    const int a_idx = lane & 31;
    const int half  = lane >> 5;
    const float* w1 = trans_weights_s1 + (size_t)t * (U_DIM * A_DIM) + a_idx;
    float h0 = 0.f, h1 = 0.f, h2 = 0.f, h3 = 0.f;
    #pragma unroll
    for (int u = 0; u < U_DIM; ++u) {
        const float wv1 = w1[u * A_DIM];               // L1/L2-hot
        h0 = fmaf(s_nte[wv][half + 0][u], wv1, h0);
        h1 = fmaf(s_nte[wv][half + 2][u], wv1, h1);
        h2 = fmaf(s_nte[wv][half + 4][u], wv1, h2);
        h3 = fmaf(s_nte[wv][half + 6][u], wv1, h3);
    }
    const float w2v = trans_weights_s2[t * A_DIM + a_idx];
    h0 = tanhf(h0) * w2v;  h1 = tanhf(h1) * w2v;
    h2 = tanhf(h2) * w2v;  h3 = tanhf(h3) * w2v;
    #pragma unroll
    for (int off = 16; off > 0; off >>= 1) {
        h0 += __shfl_down(h0, off, 32);
        h1 += __shfl_down(h1, off, 32);
        h2 += __shfl_down(h2, off, 32);
        h3 += __shfl_down(h3, off, 32);
    }
    const float sc0 = __shfl(h0, 0, 64),  sc2 = __shfl(h1, 0, 64);
    const float sc4 = __shfl(h2, 0, 64),  sc6 = __shfl(h3, 0, 64);
    const float sc1 = __shfl(h0, 32, 64), sc3 = __shfl(h1, 32, 64);
    const float sc5 = __shfl(h2, 32, 64), sc7 = __shfl(h3, 32, 64);

    // softmax over 8 types, redundant per lane (pure VALU)
    const float m = fmaxf(fmaxf(fmaxf(sc0, sc1), fmaxf(sc2, sc3)),
                          fmaxf(fmaxf(sc4, sc5), fmaxf(sc6, sc7)));
    const float x0 = __expf(sc0 - m), x1 = __expf(sc1 - m);
    const float x2 = __expf(sc2 - m), x3 = __expf(sc3 - m);
    const float x4 = __expf(sc4 - m), x5 = __expf(sc5 - m);
    const float x6 = __expf(sc6 - m), x7 = __expf(sc7 - m);
    const float inv_sum = 1.f / (x0 + x1 + x2 + x3 + x4 + x5 + x6 + x7);

    // agg[u=lane]: re-read the 8 sums from LDS (stride-1, conflict-free)
    const float agg = (x0 * s_nte[wv][0][lane] + x1 * s_nte[wv][1][lane] +
                       x2 * s_nte[wv][2][lane] + x3 * s_nte[wv][3][lane] +
                       x4 * s_nte[wv][4][lane] + x5 * s_nte[wv][5][lane] +
                       x6 * s_nte[wv][6][lane] + x7 * s_nte[wv][7][lane]) * inv_sum;
    s_agg[lane][wv] = agg;
    __syncthreads();

    // ---- cooperative matvec: 128 threads, 4 consecutive e each, float4 loads
    if (tid < 128) {
        const int e0 = tid * 4;
        int eI[G];
        #pragma unroll
        for (int g = 0; g < G; ++g)
            eI[g] = ws[WS_PERM + eBase + min(g, nE - 1)];   // L2-hot reload

        float4 v0 = *(const float4*)(node_embeddings + (size_t)train_inputs[eI[0]] * E_DIM + e0);
        float4 v1 = *(const float4*)(node_embeddings + (size_t)train_inputs[eI[1]] * E_DIM + e0);
        float4 v2 = *(const float4*)(node_embeddings + (size_t)train_inputs[eI[2]] * E_DIM + e0);
        float4 v3 = *(const float4*)(node_embeddings + (size_t)train_inputs[eI[3]] * E_DIM + e0);

        const float* wb = trans_weights + (size_t)t * (U_DIM * E_DIM) + e0;
        #pragma unroll 8
        for (int u = 0; u < U_DIM; ++u) {
            const float4 w4 = *(const float4*)(wb + (size_t)u * E_DIM);
            const float4 ag = *(const float4*)(&s_agg[u][0]);   // b128 broadcast
            v0.x = fmaf(ag.x, w4.x, v0.x); v0.y = fmaf(ag.x, w4.y, v0.y);
            v0.z = fmaf(ag.x, w4.z, v0.z); v0.w = fmaf(ag.x, w4.w, v0.w);
            v1.x = fmaf(ag.y, w4.x, v1.x); v1.y = fmaf(ag.y, w4.y, v1.y);
            v1.z = fmaf(ag.y, w4.z, v1.z); v1.w = fmaf(ag.y, w4.w, v1.w);
            v2.x = fmaf(ag.z, w4.x, v2.x); v2.y = fmaf(ag.z, w4.y, v2.y);
            v2.z = fmaf(ag.z, w4.z, v2.z); v2.w = fmaf(ag.z, w4.w, v2.w);
            v3.x = fmaf(ag.w, w4.x, v3.x); v3.y = fmaf(ag.w, w4.y, v3.y);
            v3.z = fmaf(ag.w, w4.z, v3.z); v3.w = fmaf(ag.w, w4.w, v3.w);
        }

        // per-element L2 norm: wave butterfly, then 2-wave LDS combine
        float ss0 = v0.x * v0.x + v0.y * v0.y + v0.z * v0.z + v0.w * v0.w;
        float ss1 = v1.x * v1.x + v1.y * v1.y + v1.z * v1.z + v1.w * v1.w;
        float ss2 = v2.x * v2.x + v2.y * v2.y + v2.z * v2.z + v2.w * v2.w;
        float ss3 = v3.x * v3.x + v3.y * v3.y + v3.z * v3.z + v3.w * v3.w;
        #pragma unroll
        for (int off = 32; off > 0; off >>= 1) {
            ss0 += __shfl_xor(ss0, off, 64);
            ss1 += __shfl_xor(ss1, off, 64);
            ss2 += __shfl_xor(ss2, off, 64);
            ss3 += __shfl_xor(ss3, off, 64);
        }
        if (lane == 0) {
            s_red[wv][0] = ss0; s_red[wv][1] = ss1;
            s_red[wv][2] = ss2; s_red[wv][3] = ss3;
        }
        __builtin_amdgcn_s_barrier();     // all 4 waves arrive (waves 2,3 below)

        const float iv0 = 1.f / fmaxf(sqrtf(s_red[0][0] + s_red[1][0]), 1e-12f);
        const float iv1 = 1.f / fmaxf(sqrtf(s_red[0][1] + s_red[1][1]), 1e-12f);
        const float iv2 = 1.f / fmaxf(sqrtf(s_red[0][2] + s_red[1][2]), 1e-12f);
        const float iv3 = 1.f / fmaxf(sqrtf(s_red[0][3] + s_red[1][3]), 1e-12f);

        { float4 o; o.x=v0.x*iv0; o.y=v0.y*iv0; o.z=v0.z*iv0; o.w=v0.w*iv0;
          *(float4*)(out + (size_t)eI[0] * E_DIM + e0) = o; }
        if (1 < nE) { float4 o; o.x=v1.x*iv1; o.y=v1.y*iv1; o.z=v1.z*iv1; o.w=v1.w*iv1;
          *(float4*)(out + (size_t)eI[1] * E_DIM + e0) = o; }
        if (2 < nE) { float4 o; o.x=v2.x*iv2; o.y=v2.y*iv2; o.z=v2.z*iv2; o.w=v2.w*iv2;
          *(float4*)(out + (size_t)eI[2] * E_DIM + e0) = o; }
        if (3 < nE) { float4 o; o.x=v3.x*iv3; o.y=v3.y*iv3; o.z=v3.z*iv3; o.w=v3.w*iv3;
          *(float4*)(out + (size_t)eI[3] * E_DIM + e0) = o; }
    } else {
        __builtin_amdgcn_s_barrier();     // matching barrier for waves 2,3
    }
}

// ---------------------------------------------------------------------------
// Fallback (round-2 kernel, 121us) if workspace is unavailable.
// ---------------------------------------------------------------------------
__launch_bounds__(256, 8)
__global__ void gatne_fallback(
    const float* __restrict__ node_embeddings,
    const float* __restrict__ node_type_embeddings,
    const float* __restrict__ trans_weights,
    const float* __restrict__ trans_weights_s1,
    const float* __restrict__ trans_weights_s2,
    const int*   __restrict__ train_inputs,
    const int*   __restrict__ train_types,
    const int*   __restrict__ node_neigh,
    float*       __restrict__ out)
{
    const int b    = blockIdx.x;
    const int tid  = threadIdx.x;
    const int lane = tid & 63;
    const int wv   = tid >> 6;

    __shared__ float s_nte[T_DIM][U_DIM];
    __shared__ float s_att[T_DIM];
    __shared__ float s_agg[U_DIM];
    __shared__ float s_red[4];

    const int* nn = node_neigh + (size_t)b * (T_DIM * NB);
    int my = 0;
    if (lane < 2 * NB) my = nn[wv * NB + (lane < NB ? lane : 30 + lane)];

    const int ni = train_inputs[b];
    const int ty = train_types[b];
    const int e0 = tid * 2;
    const float2 ne = *(const float2*)(node_embeddings + (size_t)ni * E_DIM + e0);

    float a0 = 0.f, a1 = 0.f;
    #pragma unroll
    for (int n = 0; n < NB; ++n) {
        const int i0 = __shfl(my, n, 64);
        const int i1 = __shfl(my, NB + n, 64);
        a0 += node_type_embeddings[(size_t)i0 * (T_DIM * U_DIM) + wv * U_DIM + lane];
        a1 += node_type_embeddings[(size_t)i1 * (T_DIM * U_DIM) + (wv + 4) * U_DIM + lane];
    }
    s_nte[wv][lane]     = a0;
    s_nte[wv + 4][lane] = a1;
    __syncthreads();

    {
        const int t = tid >> 5;
        const int a = tid & 31;
        const float* w1 = trans_weights_s1 + (size_t)ty * (U_DIM * A_DIM) + a;
        float h = 0.f;
        #pragma unroll
        for (int u = 0; u < U_DIM; ++u)
            h = fmaf(s_nte[t][u], w1[u * A_DIM], h);
        float val = tanhf(h) * trans_weights_s2[ty * A_DIM + a];
        #pragma unroll
        for (int off = 16; off > 0; off >>= 1)
            val += __shfl_down(val, off, 32);
        if (a == 0) s_att[t] = val;
    }
    __syncthreads();

    if (tid < U_DIM) {
        float sc0 = s_att[0], sc1 = s_att[1], sc2 = s_att[2], sc3 = s_att[3];
        float sc4 = s_att[4], sc5 = s_att[5], sc6 = s_att[6], sc7 = s_att[7];
        const float m = fmaxf(fmaxf(fmaxf(sc0, sc1), fmaxf(sc2, sc3)),
                              fmaxf(fmaxf(sc4, sc5), fmaxf(sc6, sc7)));
        const float x0 = __expf(sc0 - m), x1 = __expf(sc1 - m);
        const float x2 = __expf(sc2 - m), x3 = __expf(sc3 - m);
        const float x4 = __expf(sc4 - m), x5 = __expf(sc5 - m);
        const float x6 = __expf(sc6 - m), x7 = __expf(sc7 - m);
        const float inv_sum = 1.f / (x0 + x1 + x2 + x3 + x4 + x5 + x6 + x7);
        const float acc = x0 * s_nte[0][tid] + x1 * s_nte[1][tid]
                        + x2 * s_nte[2][tid] + x3 * s_nte[3][tid]
                        + x4 * s_nte[4][tid] + x5 * s_nte[5][tid]
                        + x6 * s_nte[6][tid] + x7 * s_nte[7][tid];
        s_agg[tid] = acc * inv_sum;
    }
    __syncthreads();

    const float* wb = trans_weights + (size_t)ty * (U_DIM * E_DIM) + e0;
    float v0 = ne.x, v1 = ne.y;
    #pragma unroll 16
    for (int u = 0; u < U_DIM; ++u) {
        const float av = s_agg[u];
        const float2 w2v = *(const float2*)(wb + (size_t)u * E_DIM);
        v0 = fmaf(av, w2v.x, v0);
        v1 = fmaf(av, w2v.y, v1);
    }

    float ss = v0 * v0 + v1 * v1;
    #pragma unroll
    for (int off = 32; off > 0; off >>= 1)
        ss += __shfl_xor(ss, off, 64);
    if (lane == 0) s_red[wv] = ss;
    __syncthreads();
    const float total = s_red[0] + s_red[1] + s_red[2] + s_red[3];
    const float inv = 1.f / fmaxf(sqrtf(total), 1e-12f);

    float2 o; o.x = v0 * inv; o.y = v1 * inv;
    *(float2*)(out + (size_t)b * E_DIM + e0) = o;
}

extern "C" void kernel_launch(void* const* d_in, const int* in_sizes, int n_in,
                              void* d_out, int out_size, void* d_ws, size_t ws_size,
                              hipStream_t stream) {
    const float* node_embeddings      = (const float*)d_in[0];
    const float* node_type_embeddings = (const float*)d_in[1];
    const float* trans_weights        = (const float*)d_in[2];
    const float* trans_weights_s1     = (const float*)d_in[3];
    const float* trans_weights_s2     = (const float*)d_in[4];
    const int*   train_inputs         = (const int*)d_in[5];
    const int*   train_types          = (const int*)d_in[6];
    const int*   node_neigh           = (const int*)d_in[7];
    float* out = (float*)d_out;

    if (d_ws != nullptr && ws_size >= WS_INTS * sizeof(int)) {
        bucket_kernel<<<1, 1024, 0, stream>>>(train_types, (int*)d_ws);
        gatne_main<<<MAX_BLOCKS, 256, 0, stream>>>(
            node_embeddings, node_type_embeddings, trans_weights,
            trans_weights_s1, trans_weights_s2,
            train_inputs, node_neigh, (const int*)d_ws, out);
    } else {
        gatne_fallback<<<BATCH, 256, 0, stream>>>(
            node_embeddings, node_type_embeddings, trans_weights,
            trans_weights_s1, trans_weights_s2,
            train_inputs, train_types, node_neigh, out);
    }
}

// Round 5
// 422.285 us; speedup vs baseline: 1.6129x; 1.4284x over previous
//
#include <hip/hip_runtime.h>

#define E_DIM 512
#define U_DIM 64
#define T_DIM 8
#define A_DIM 32
#define NB    10
#define BATCH 8192
#define G2    8                        // elements per stage-2 block
#define S2_BLOCKS (BATCH / G2 + T_DIM)

// workspace layout
#define WS_PERM  0                     // [8192] ints: permutation grouped by type
#define WS_START 8192                  // [9] ints: element prefix per type
#define WS_BLK   8201                  // [9] ints: stage-2 block prefix per type
#define WS_IPAD  8256                  // pad; floats (agg[B][64]) start here
#define WS_TOTAL_BYTES ((size_t)(WS_IPAD + BATCH * U_DIM) * 4)

// ---------------------------------------------------------------------------
// Pass 0: counting sort of batch elements by type. Order within a type is
// irrelevant (each element's output depends only on its own inputs), so
// atomic nondeterminism in the permutation does not change results.
// ---------------------------------------------------------------------------
__global__ void bucket_kernel(const int* __restrict__ train_types,
                              int* __restrict__ ws)
{
    __shared__ int cnt[T_DIM], offs[T_DIM], startS[T_DIM];
    const int tid  = threadIdx.x;        // 1024 threads
    const int lane = tid & 63;

    if (tid < T_DIM) { cnt[tid] = 0; offs[tid] = 0; }
    __syncthreads();

    int ty[8];
    #pragma unroll
    for (int it = 0; it < 8; ++it) ty[it] = train_types[tid + it * 1024];

    #pragma unroll
    for (int it = 0; it < 8; ++it) {
        #pragma unroll
        for (int t = 0; t < T_DIM; ++t) {
            const unsigned long long m = __ballot(ty[it] == t);
            if (m && lane == __ffsll((unsigned long long)m) - 1)
                atomicAdd(&cnt[t], __popcll(m));
        }
    }
    __syncthreads();

    if (tid == 0) {
        int s = 0, bs = 0;
        for (int t = 0; t < T_DIM; ++t) {
            startS[t] = s;
            ws[WS_START + t] = s;
            ws[WS_BLK + t]   = bs;
            s  += cnt[t];
            bs += (cnt[t] + G2 - 1) / G2;
        }
        ws[WS_START + T_DIM] = s;
        ws[WS_BLK + T_DIM]   = bs;
    }
    __syncthreads();

    #pragma unroll
    for (int it = 0; it < 8; ++it) {
        const int idx = tid + it * 1024;
        const int t   = ty[it];
        #pragma unroll
        for (int tt = 0; tt < T_DIM; ++tt) {
            const unsigned long long m = __ballot(t == tt);
            if (t == tt) {
                const int leader = __ffsll((unsigned long long)m) - 1;
                int base;
                if (lane == leader) base = atomicAdd(&offs[tt], __popcll(m));
                base = __shfl(base, leader, 64);
                const int rank = __popcll(m & ((1ull << lane) - 1ull));
                ws[WS_PERM + startS[tt] + base + rank] = idx;
            }
        }
    }
}

// ---------------------------------------------------------------------------
// Stage 1: per-element blocks (8192), EXACT round-2 structure (proven clean:
// 121us total incl. matvec, WRITE_SIZE 16MB) minus the matvec. Writes
// agg[b][64] (2MB) to workspace.
// ---------------------------------------------------------------------------
__launch_bounds__(256, 8)
__global__ void gatne_stage1(
    const float* __restrict__ node_type_embeddings, // [N, 8, 64]
    const float* __restrict__ trans_weights_s1,     // [8, 64, 32]
    const float* __restrict__ trans_weights_s2,     // [8, 32]
    const int*   __restrict__ train_types,          // [B]
    const int*   __restrict__ node_neigh,           // [B, 8, 10]
    float*       __restrict__ agg_out)              // [B, 64] in ws
{
    const int b    = blockIdx.x;
    const int tid  = threadIdx.x;
    const int lane = tid & 63;
    const int wv   = tid >> 6;     // wave 0..3 handles types wv and wv+4

    __shared__ float s_nte[T_DIM][U_DIM];   // 2 KB
    __shared__ float s_att[T_DIM];

    const int* nn = node_neigh + (size_t)b * (T_DIM * NB);
    int my = 0;
    if (lane < 2 * NB) my = nn[wv * NB + (lane < NB ? lane : 30 + lane)];

    const int ty = train_types[b];

    float a0 = 0.f, a1 = 0.f;
    #pragma unroll
    for (int n = 0; n < NB; ++n) {
        const int i0 = __shfl(my, n, 64);
        const int i1 = __shfl(my, NB + n, 64);
        a0 += node_type_embeddings[(size_t)i0 * (T_DIM * U_DIM) + wv * U_DIM + lane];
        a1 += node_type_embeddings[(size_t)i1 * (T_DIM * U_DIM) + (wv + 4) * U_DIM + lane];
    }
    s_nte[wv][lane]     = a0;
    s_nte[wv + 4][lane] = a1;
    __syncthreads();

    {
        const int t = tid >> 5;
        const int a = tid & 31;
        const float* w1 = trans_weights_s1 + (size_t)ty * (U_DIM * A_DIM) + a;
        float h = 0.f;
        #pragma unroll
        for (int u = 0; u < U_DIM; ++u)
            h = fmaf(s_nte[t][u], w1[u * A_DIM], h);
        float val = tanhf(h) * trans_weights_s2[ty * A_DIM + a];
        #pragma unroll
        for (int off = 16; off > 0; off >>= 1)
            val += __shfl_down(val, off, 32);
        if (a == 0) s_att[t] = val;
    }
    __syncthreads();

    if (tid < U_DIM) {
        const float sc0 = s_att[0], sc1 = s_att[1], sc2 = s_att[2], sc3 = s_att[3];
        const float sc4 = s_att[4], sc5 = s_att[5], sc6 = s_att[6], sc7 = s_att[7];
        const float m = fmaxf(fmaxf(fmaxf(sc0, sc1), fmaxf(sc2, sc3)),
                              fmaxf(fmaxf(sc4, sc5), fmaxf(sc6, sc7)));
        const float x0 = __expf(sc0 - m), x1 = __expf(sc1 - m);
        const float x2 = __expf(sc2 - m), x3 = __expf(sc3 - m);
        const float x4 = __expf(sc4 - m), x5 = __expf(sc5 - m);
        const float x6 = __expf(sc6 - m), x7 = __expf(sc7 - m);
        const float inv_sum = 1.f / (x0 + x1 + x2 + x3 + x4 + x5 + x6 + x7);
        const float acc = x0 * s_nte[0][tid] + x1 * s_nte[1][tid]
                        + x2 * s_nte[2][tid] + x3 * s_nte[3][tid]
                        + x4 * s_nte[4][tid] + x5 * s_nte[5][tid]
                        + x6 * s_nte[6][tid] + x7 * s_nte[7][tid];
        agg_out[(size_t)b * U_DIM + tid] = acc * inv_sum;   // 256B coalesced
    }
}

// ---------------------------------------------------------------------------
// Stage 2: grouped matvec. G2=8 same-type elements per block; half-block
// (128 threads, float4 lanes over e) computes 4 elements from ONE shared
// w[ty] float4 stream -> 8x less L2 w-traffic than per-element (1.07GB->134MB).
// ---------------------------------------------------------------------------
__launch_bounds__(256, 8)
__global__ void gatne_stage2(
    const float* __restrict__ node_embeddings,      // [N, 512]
    const float* __restrict__ trans_weights,        // [8, 64, 512]
    const int*   __restrict__ train_inputs,         // [B]
    const int*   __restrict__ ws_i,
    const float* __restrict__ agg,                  // [B, 64] in ws
    float*       __restrict__ out)                  // [B, 512]
{
    const int tid  = threadIdx.x;
    const int lane = tid & 63;
    const int wv   = tid >> 6;      // 0..3
    const int half = tid >> 7;      // 0,1 ; half h owns elements 4h..4h+3
    const int g0   = half * 4;
    const int e0   = (tid & 127) * 4;

    __shared__ __align__(16) float s_agg[U_DIM][G2];   // [64][8] = 2 KB
    __shared__ float s_red[4][4];

    const int j = blockIdx.x;
    if (j >= ws_i[WS_BLK + T_DIM]) return;

    int t = 0;
    #pragma unroll
    for (int k = 1; k < T_DIM; ++k) if (j >= ws_i[WS_BLK + k]) t = k;
    const int eBase = ws_i[WS_START + t] + (j - ws_i[WS_BLK + t]) * G2;
    const int nE    = min(G2, ws_i[WS_START + t + 1] - eBase);

    // cooperative agg->LDS: 32-lane group per element, float2 each (coalesced)
    {
        const int g  = tid >> 5;                       // 0..7
        const int u2 = (tid & 31) * 2;
        const int eg = ws_i[WS_PERM + eBase + min(g, nE - 1)];
        const float2 v = *(const float2*)(agg + (size_t)eg * U_DIM + u2);
        s_agg[u2][g]     = v.x;
        s_agg[u2 + 1][g] = v.y;
    }

    // this half's 4 element ids (static registers, no runtime-indexed arrays)
    const int eA = ws_i[WS_PERM + eBase + min(g0 + 0, nE - 1)];
    const int eB = ws_i[WS_PERM + eBase + min(g0 + 1, nE - 1)];
    const int eC = ws_i[WS_PERM + eBase + min(g0 + 2, nE - 1)];
    const int eD = ws_i[WS_PERM + eBase + min(g0 + 3, nE - 1)];

    float4 v0 = *(const float4*)(node_embeddings + (size_t)train_inputs[eA] * E_DIM + e0);
    float4 v1 = *(const float4*)(node_embeddings + (size_t)train_inputs[eB] * E_DIM + e0);
    float4 v2 = *(const float4*)(node_embeddings + (size_t)train_inputs[eC] * E_DIM + e0);
    float4 v3 = *(const float4*)(node_embeddings + (size_t)train_inputs[eD] * E_DIM + e0);

    __syncthreads();   // s_agg ready

    const float* wb = trans_weights + (size_t)t * (U_DIM * E_DIM) + e0;
    #pragma unroll 4
    for (int u = 0; u < U_DIM; ++u) {
        const float4 w4 = *(const float4*)(wb + (size_t)u * E_DIM);
        const float4 ag = *(const float4*)(&s_agg[u][g0]);   // b128 broadcast
        v0.x = fmaf(ag.x, w4.x, v0.x); v0.y = fmaf(ag.x, w4.y, v0.y);
        v0.z = fmaf(ag.x, w4.z, v0.z); v0.w = fmaf(ag.x, w4.w, v0.w);
        v1.x = fmaf(ag.y, w4.x, v1.x); v1.y = fmaf(ag.y, w4.y, v1.y);
        v1.z = fmaf(ag.y, w4.z, v1.z); v1.w = fmaf(ag.y, w4.w, v1.w);
        v2.x = fmaf(ag.z, w4.x, v2.x); v2.y = fmaf(ag.z, w4.y, v2.y);
        v2.z = fmaf(ag.z, w4.z, v2.z); v2.w = fmaf(ag.z, w4.w, v2.w);
        v3.x = fmaf(ag.w, w4.x, v3.x); v3.y = fmaf(ag.w, w4.y, v3.y);
        v3.z = fmaf(ag.w, w4.z, v3.z); v3.w = fmaf(ag.w, w4.w, v3.w);
    }

    // per-element L2 norm: wave butterfly, then pair-of-waves LDS combine
    float ss0 = v0.x*v0.x + v0.y*v0.y + v0.z*v0.z + v0.w*v0.w;
    float ss1 = v1.x*v1.x + v1.y*v1.y + v1.z*v1.z + v1.w*v1.w;
    float ss2 = v2.x*v2.x + v2.y*v2.y + v2.z*v2.z + v2.w*v2.w;
    float ss3 = v3.x*v3.x + v3.y*v3.y + v3.z*v3.z + v3.w*v3.w;
    #pragma unroll
    for (int off = 32; off > 0; off >>= 1) {
        ss0 += __shfl_xor(ss0, off, 64);
        ss1 += __shfl_xor(ss1, off, 64);
        ss2 += __shfl_xor(ss2, off, 64);
        ss3 += __shfl_xor(ss3, off, 64);
    }
    if (lane == 0) {
        s_red[wv][0] = ss0; s_red[wv][1] = ss1;
        s_red[wv][2] = ss2; s_red[wv][3] = ss3;
    }
    __syncthreads();

    const int h2 = half * 2;
    const float iv0 = 1.f / fmaxf(sqrtf(s_red[h2][0] + s_red[h2+1][0]), 1e-12f);
    const float iv1 = 1.f / fmaxf(sqrtf(s_red[h2][1] + s_red[h2+1][1]), 1e-12f);
    const float iv2 = 1.f / fmaxf(sqrtf(s_red[h2][2] + s_red[h2+1][2]), 1e-12f);
    const float iv3 = 1.f / fmaxf(sqrtf(s_red[h2][3] + s_red[h2+1][3]), 1e-12f);

    // stores masked so clamped duplicates (g >= nE) don't write
    if (g0 + 0 < nE) { float4 o; o.x=v0.x*iv0; o.y=v0.y*iv0; o.z=v0.z*iv0; o.w=v0.w*iv0;
        *(float4*)(out + (size_t)eA * E_DIM + e0) = o; }
    if (g0 + 1 < nE) { float4 o; o.x=v1.x*iv1; o.y=v1.y*iv1; o.z=v1.z*iv1; o.w=v1.w*iv1;
        *(float4*)(out + (size_t)eB * E_DIM + e0) = o; }
    if (g0 + 2 < nE) { float4 o; o.x=v2.x*iv2; o.y=v2.y*iv2; o.z=v2.z*iv2; o.w=v2.w*iv2;
        *(float4*)(out + (size_t)eC * E_DIM + e0) = o; }
    if (g0 + 3 < nE) { float4 o; o.x=v3.x*iv3; o.y=v3.y*iv3; o.z=v3.z*iv3; o.w=v3.w*iv3;
        *(float4*)(out + (size_t)eD * E_DIM + e0) = o; }
}

// ---------------------------------------------------------------------------
// Fallback (round-2 kernel, proven 121us) if workspace is unavailable.
// ---------------------------------------------------------------------------
__launch_bounds__(256, 8)
__global__ void gatne_fallback(
    const float* __restrict__ node_embeddings,
    const float* __restrict__ node_type_embeddings,
    const float* __restrict__ trans_weights,
    const float* __restrict__ trans_weights_s1,
    const float* __restrict__ trans_weights_s2,
    const int*   __restrict__ train_inputs,
    const int*   __restrict__ train_types,
    const int*   __restrict__ node_neigh,
    float*       __restrict__ out)
{
    const int b    = blockIdx.x;
    const int tid  = threadIdx.x;
    const int lane = tid & 63;
    const int wv   = tid >> 6;

    __shared__ float s_nte[T_DIM][U_DIM];
    __shared__ float s_att[T_DIM];
    __shared__ float s_agg[U_DIM];
    __shared__ float s_red[4];

    const int* nn = node_neigh + (size_t)b * (T_DIM * NB);
    int my = 0;
    if (lane < 2 * NB) my = nn[wv * NB + (lane < NB ? lane : 30 + lane)];

    const int ni = train_inputs[b];
    const int ty = train_types[b];
    const int e0 = tid * 2;
    const float2 ne = *(const float2*)(node_embeddings + (size_t)ni * E_DIM + e0);

    float a0 = 0.f, a1 = 0.f;
    #pragma unroll
    for (int n = 0; n < NB; ++n) {
        const int i0 = __shfl(my, n, 64);
        const int i1 = __shfl(my, NB + n, 64);
        a0 += node_type_embeddings[(size_t)i0 * (T_DIM * U_DIM) + wv * U_DIM + lane];
        a1 += node_type_embeddings[(size_t)i1 * (T_DIM * U_DIM) + (wv + 4) * U_DIM + lane];
    }
    s_nte[wv][lane]     = a0;
    s_nte[wv + 4][lane] = a1;
    __syncthreads();

    {
        const int t = tid >> 5;
        const int a = tid & 31;
        const float* w1 = trans_weights_s1 + (size_t)ty * (U_DIM * A_DIM) + a;
        float h = 0.f;
        #pragma unroll
        for (int u = 0; u < U_DIM; ++u)
            h = fmaf(s_nte[t][u], w1[u * A_DIM], h);
        float val = tanhf(h) * trans_weights_s2[ty * A_DIM + a];
        #pragma unroll
        for (int off = 16; off > 0; off >>= 1)
            val += __shfl_down(val, off, 32);
        if (a == 0) s_att[t] = val;
    }
    __syncthreads();

    if (tid < U_DIM) {
        const float sc0 = s_att[0], sc1 = s_att[1], sc2 = s_att[2], sc3 = s_att[3];
        const float sc4 = s_att[4], sc5 = s_att[5], sc6 = s_att[6], sc7 = s_att[7];
        const float m = fmaxf(fmaxf(fmaxf(sc0, sc1), fmaxf(sc2, sc3)),
                              fmaxf(fmaxf(sc4, sc5), fmaxf(sc6, sc7)));
        const float x0 = __expf(sc0 - m), x1 = __expf(sc1 - m);
        const float x2 = __expf(sc2 - m), x3 = __expf(sc3 - m);
        const float x4 = __expf(sc4 - m), x5 = __expf(sc5 - m);
        const float x6 = __expf(sc6 - m), x7 = __expf(sc7 - m);
        const float inv_sum = 1.f / (x0 + x1 + x2 + x3 + x4 + x5 + x6 + x7);
        const float acc = x0 * s_nte[0][tid] + x1 * s_nte[1][tid]
                        + x2 * s_nte[2][tid] + x3 * s_nte[3][tid]
                        + x4 * s_nte[4][tid] + x5 * s_nte[5][tid]
                        + x6 * s_nte[6][tid] + x7 * s_nte[7][tid];
        s_agg[tid] = acc * inv_sum;
    }
    __syncthreads();

    const float* wb = trans_weights + (size_t)ty * (U_DIM * E_DIM) + e0;
    float v0 = ne.x, v1 = ne.y;
    #pragma unroll 16
    for (int u = 0; u < U_DIM; ++u) {
        const float av = s_agg[u];
        const float2 w2v = *(const float2*)(wb + (size_t)u * E_DIM);
        v0 = fmaf(av, w2v.x, v0);
        v1 = fmaf(av, w2v.y, v1);
    }

    float ss = v0 * v0 + v1 * v1;
    #pragma unroll
    for (int off = 32; off > 0; off >>= 1)
        ss += __shfl_xor(ss, off, 64);
    if (lane == 0) s_red[wv] = ss;
    __syncthreads();
    const float total = s_red[0] + s_red[1] + s_red[2] + s_red[3];
    const float inv = 1.f / fmaxf(sqrtf(total), 1e-12f);

    float2 o; o.x = v0 * inv; o.y = v1 * inv;
    *(float2*)(out + (size_t)b * E_DIM + e0) = o;
}

extern "C" void kernel_launch(void* const* d_in, const int* in_sizes, int n_in,
                              void* d_out, int out_size, void* d_ws, size_t ws_size,
                              hipStream_t stream) {
    const float* node_embeddings      = (const float*)d_in[0];
    const float* node_type_embeddings = (const float*)d_in[1];
    const float* trans_weights        = (const float*)d_in[2];
    const float* trans_weights_s1     = (const float*)d_in[3];
    const float* trans_weights_s2     = (const float*)d_in[4];
    const int*   train_inputs         = (const int*)d_in[5];
    const int*   train_types          = (const int*)d_in[6];
    const int*   node_neigh           = (const int*)d_in[7];
    float* out = (float*)d_out;

    if (d_ws != nullptr && ws_size >= WS_TOTAL_BYTES) {
        int*   wsi = (int*)d_ws;
        float* agg = (float*)d_ws + WS_IPAD;
        bucket_kernel<<<1, 1024, 0, stream>>>(train_types, wsi);
        gatne_stage1<<<BATCH, 256, 0, stream>>>(
            node_type_embeddings, trans_weights_s1, trans_weights_s2,
            train_types, node_neigh, agg);
        gatne_stage2<<<S2_BLOCKS, 256, 0, stream>>>(
            node_embeddings, trans_weights, train_inputs, wsi, agg, out);
    } else {
        gatne_fallback<<<BATCH, 256, 0, stream>>>(
            node_embeddings, node_type_embeddings, trans_weights,
            trans_weights_s1, trans_weights_s2,
            train_inputs, train_types, node_neigh, out);
    }
}